// Round 1
// baseline (1822.571 us; speedup 1.0000x reference)
//
#include <hip/hip_runtime.h>
#include <hip/hip_bf16.h>
#include <math.h>

// Problem constants (from reference)
#define LEN_TOT 21760
#define BATCH 2
#define MROWS (BATCH * LEN_TOT)   // 43520
#define DMODEL 256
#define DFFN 1024

// ---------------------------------------------------------------------------
// LayerNorm (+ optional additive term, e.g. pos): y = LN(x)*g + b [+ add]
// One 64-lane wave per 256-float row; 4 rows per 256-thread block.
// ---------------------------------------------------------------------------
__global__ __launch_bounds__(256) void ln_kernel(
    const float* __restrict__ x, const float* __restrict__ g,
    const float* __restrict__ bb, const float* __restrict__ addv,
    float* __restrict__ y)
{
    int row  = blockIdx.x * 4 + (threadIdx.x >> 6);
    int lane = threadIdx.x & 63;
    size_t base = (size_t)row * DMODEL + lane * 4;
    float4 v = *(const float4*)(x + base);

    float s = v.x + v.y + v.z + v.w;
    #pragma unroll
    for (int o = 32; o; o >>= 1) s += __shfl_xor(s, o, 64);
    float mu = s * (1.0f / 256.0f);

    float d0 = v.x - mu, d1 = v.y - mu, d2 = v.z - mu, d3 = v.w - mu;
    float vs = d0*d0 + d1*d1 + d2*d2 + d3*d3;
    #pragma unroll
    for (int o = 32; o; o >>= 1) vs += __shfl_xor(vs, o, 64);
    float rstd = rsqrtf(vs * (1.0f / 256.0f) + 1e-5f);

    float4 gv = *(const float4*)(g  + lane * 4);
    float4 bv = *(const float4*)(bb + lane * 4);
    float4 o;
    o.x = d0 * rstd * gv.x + bv.x;
    o.y = d1 * rstd * gv.y + bv.y;
    o.z = d2 * rstd * gv.z + bv.z;
    o.w = d3 * rstd * gv.w + bv.w;
    if (addv) {
        float4 av = *(const float4*)(addv + base);
        o.x += av.x; o.y += av.y; o.z += av.z; o.w += av.w;
    }
    *(float4*)(y + base) = o;
}

// ---------------------------------------------------------------------------
// fp32 tiled GEMM: C[M,N] = act(A[M,K] @ W[K,N] + bias) [+ res]
// BM=64, BN=64, BK=16; 256 threads; each thread 4x4 outputs.
// Requires M%64==0, N%64==0, K%16==0.
// ---------------------------------------------------------------------------
template<int GELU_ACT, int HAS_RES>
__global__ __launch_bounds__(256) void gemm64(
    const float* __restrict__ A, const float* __restrict__ Wm,
    const float* __restrict__ bias, const float* __restrict__ res,
    float* __restrict__ C, int M, int N, int K)
{
    constexpr int BM = 64, BN = 64, BK = 16;
    __shared__ float As[BK][BM + 4];
    __shared__ float Bs[BK][BN + 4];

    const int tid = threadIdx.x;
    const int tx = tid & 15, ty = tid >> 4;
    const int m0 = blockIdx.y * BM, n0 = blockIdx.x * BN;

    float acc[4][4];
    #pragma unroll
    for (int i = 0; i < 4; i++)
        #pragma unroll
        for (int j = 0; j < 4; j++) acc[i][j] = 0.0f;

    const int ar  = tid >> 2;          // 0..63 (A tile row)
    const int ac4 = (tid & 3) << 2;    // 0,4,8,12 (A tile col)
    const int wr  = tid >> 4;          // 0..15 (W tile row)
    const int wc  = (tid & 15) << 2;   // 0..60 (W tile col)

    for (int k0 = 0; k0 < K; k0 += BK) {
        float4 av = *(const float4*)(A + (size_t)(m0 + ar) * K + k0 + ac4);
        As[ac4 + 0][ar] = av.x;
        As[ac4 + 1][ar] = av.y;
        As[ac4 + 2][ar] = av.z;
        As[ac4 + 3][ar] = av.w;
        float4 wv = *(const float4*)(Wm + (size_t)(k0 + wr) * N + n0 + wc);
        *(float4*)&Bs[wr][wc] = wv;
        __syncthreads();

        #pragma unroll
        for (int k = 0; k < BK; k++) {
            float4 a = *(const float4*)&As[k][ty << 2];
            float4 b = *(const float4*)&Bs[k][tx << 2];
            acc[0][0] += a.x * b.x; acc[0][1] += a.x * b.y;
            acc[0][2] += a.x * b.z; acc[0][3] += a.x * b.w;
            acc[1][0] += a.y * b.x; acc[1][1] += a.y * b.y;
            acc[1][2] += a.y * b.z; acc[1][3] += a.y * b.w;
            acc[2][0] += a.z * b.x; acc[2][1] += a.z * b.y;
            acc[2][2] += a.z * b.z; acc[2][3] += a.z * b.w;
            acc[3][0] += a.w * b.x; acc[3][1] += a.w * b.y;
            acc[3][2] += a.w * b.z; acc[3][3] += a.w * b.w;
        }
        __syncthreads();
    }

    float4 bb = *(const float4*)(bias + n0 + (tx << 2));
    #pragma unroll
    for (int i = 0; i < 4; i++) {
        int row = m0 + (ty << 2) + i;
        float4 o;
        o.x = acc[i][0] + bb.x;
        o.y = acc[i][1] + bb.y;
        o.z = acc[i][2] + bb.z;
        o.w = acc[i][3] + bb.w;
        if (GELU_ACT) {
            const float inv_sqrt2 = 0.7071067811865476f;
            o.x = 0.5f * o.x * (1.0f + erff(o.x * inv_sqrt2));
            o.y = 0.5f * o.y * (1.0f + erff(o.y * inv_sqrt2));
            o.z = 0.5f * o.z * (1.0f + erff(o.z * inv_sqrt2));
            o.w = 0.5f * o.w * (1.0f + erff(o.w * inv_sqrt2));
        }
        if (HAS_RES) {
            float4 rv = *(const float4*)(res + (size_t)row * N + n0 + (tx << 2));
            o.x += rv.x; o.y += rv.y; o.z += rv.z; o.w += rv.w;
        }
        *(float4*)(C + (size_t)row * N + n0 + (tx << 2)) = o;
    }
}

// ---------------------------------------------------------------------------
// Fused softmax + multi-scale deformable bilinear sampling.
// One 32-lane subgroup per (b, q, head); lane = channel d (HEAD_DIM=32).
// value:  [B, LEN, 8, 32]   offs: [B,LEN,8,4,4,2] (32/row-group)
// logits: [B, LEN, 8, 16]   refp: [B, LEN, 4, 2]
// out:    [B, LEN, 8, 32]  (== [B, LEN, 256])
// ---------------------------------------------------------------------------
__global__ __launch_bounds__(256) void msdeform_kernel(
    const float* __restrict__ value, const float* __restrict__ offs,
    const float* __restrict__ logits, const float* __restrict__ refp,
    float* __restrict__ out)
{
    const int HS[4] = {128, 64, 32, 16};
    const int ST[4] = {0, 16384, 20480, 21504};

    int gid = blockIdx.x * 8 + (threadIdx.x >> 5);  // (b*LEN + q)*8 + m
    int d   = threadIdx.x & 31;
    int bq  = gid >> 3;                  // b*LEN + q
    int b   = (bq >= LEN_TOT) ? 1 : 0;
    size_t base = (size_t)gid;

    // fused softmax over the 16 (level,point) logits
    float logit = (d < 16) ? logits[base * 16 + d] : -3.4e38f;
    float mx = logit;
    #pragma unroll
    for (int o = 16; o; o >>= 1) mx = fmaxf(mx, __shfl_xor(mx, o, 32));
    float e = (d < 16) ? expf(logit - mx) : 0.0f;
    float se = e;
    #pragma unroll
    for (int o = 16; o; o >>= 1) se += __shfl_xor(se, o, 32);
    float prob = e / se;

    float off = offs[base * 32 + d];     // lane d holds one of the 32 offset scalars

    float acc = 0.0f;
    #pragma unroll
    for (int i = 0; i < 16; i++) {
        int lvl = i >> 2;
        float w  = __shfl(prob, i, 32);
        float ox = __shfl(off, 2 * i, 32);
        float oy = __shfl(off, 2 * i + 1, 32);
        int Wl = HS[lvl], Hl = HS[lvl];
        float refx = refp[(size_t)(bq * 4 + lvl) * 2 + 0];
        float refy = refp[(size_t)(bq * 4 + lvl) * 2 + 1];
        // grid_sample align_corners=False: x = loc_x*W - 0.5
        float xs = (refx + ox / (float)Wl) * (float)Wl - 0.5f;
        float ys = (refy + oy / (float)Hl) * (float)Hl - 0.5f;
        float xf = floorf(xs), yf = floorf(ys);
        int x0 = (int)xf, y0 = (int)yf;
        float wx = xs - xf, wy = ys - yf;

        bool xin0 = (x0 >= 0) && (x0 < Wl);
        bool xin1 = (x0 + 1 >= 0) && (x0 + 1 < Wl);
        bool yin0 = (y0 >= 0) && (y0 < Hl);
        bool yin1 = (y0 + 1 >= 0) && (y0 + 1 < Hl);

        // value[b, start + y*W + x, m, d]; (b*LEN+loc)*256 + m*32 + d
        size_t vb = ((size_t)b * LEN_TOT + ST[lvl]) * 256 + (gid & 7) * 32 + d;
        float v00 = 0.0f, v01 = 0.0f, v10 = 0.0f, v11 = 0.0f;
        if (yin0) {
            size_t r = vb + (size_t)y0 * Wl * 256;
            if (xin0) v00 = value[r + (size_t)x0 * 256];
            if (xin1) v01 = value[r + (size_t)(x0 + 1) * 256];
        }
        if (yin1) {
            size_t r = vb + (size_t)(y0 + 1) * Wl * 256;
            if (xin0) v10 = value[r + (size_t)x0 * 256];
            if (xin1) v11 = value[r + (size_t)(x0 + 1) * 256];
        }
        float samp = (v00 * (1.0f - wx) + v01 * wx) * (1.0f - wy)
                   + (v10 * (1.0f - wx) + v11 * wx) * wy;
        acc = fmaf(w, samp, acc);
    }
    out[base * 32 + d] = acc;
}

// ---------------------------------------------------------------------------
// kernel_launch
// ---------------------------------------------------------------------------
extern "C" void kernel_launch(void* const* d_in, const int* in_sizes, int n_in,
                              void* d_out, int out_size, void* d_ws, size_t ws_size,
                              hipStream_t stream)
{
    const float* src  = (const float*)d_in[0];
    const float* pos  = (const float*)d_in[1];
    const float* refp = (const float*)d_in[2];
    // d_in[3] spatial_shapes, d_in[4] level_start_index: hardcoded constants
    const float* n1g = (const float*)d_in[5];
    const float* n1b = (const float*)d_in[6];
    const float* n2g = (const float*)d_in[7];
    const float* n2b = (const float*)d_in[8];
    const float* Wv  = (const float*)d_in[9];
    const float* bv  = (const float*)d_in[10];
    const float* Wof = (const float*)d_in[11];
    const float* bof = (const float*)d_in[12];
    const float* Wat = (const float*)d_in[13];
    const float* bat = (const float*)d_in[14];
    const float* Wo  = (const float*)d_in[15];
    const float* bo  = (const float*)d_in[16];
    const float* Wf1 = (const float*)d_in[17];
    const float* bf1 = (const float*)d_in[18];
    const float* Wf2 = (const float*)d_in[19];
    const float* bf2 = (const float*)d_in[20];
    float* out = (float*)d_out;

    float* ws = (float*)d_ws;
    const int M = MROWS;               // 43520
    float* P0 = ws;                                  // q -> sampled      [M,256]
    float* P1 = P0 + (size_t)M * 256;                // value -> src2     [M,256]
    float* P2 = P1 + (size_t)M * 256;                // offsets -> h0(LN2)[M,256]
    float* P3 = P2 + (size_t)M * 256;                // attn logits       [M,128]
    float* P4 = P3 + (size_t)M * 128;                // FFN hidden chunk  [Mc,1024]

    // 1) q = LN1(src) + pos
    ln_kernel<<<M / 4, 256, 0, stream>>>(src, n1g, n1b, pos, P0);
    // 2) value = src @ W_value + b_value  (un-normed src, per reference)
    gemm64<0, 0><<<dim3(256 / 64, M / 64), 256, 0, stream>>>(src, Wv, bv, nullptr, P1, M, 256, 256);
    // 3) offsets = q @ W_off + b_off
    gemm64<0, 0><<<dim3(256 / 64, M / 64), 256, 0, stream>>>(P0, Wof, bof, nullptr, P2, M, 256, 256);
    // 4) attn logits = q @ W_attn + b_attn
    gemm64<0, 0><<<dim3(128 / 64, M / 64), 256, 0, stream>>>(P0, Wat, bat, nullptr, P3, M, 128, 256);
    // 5) fused softmax + deformable sampling -> sampled (overwrites q in P0)
    msdeform_kernel<<<(M * 8) / 8, 256, 0, stream>>>(P1, P2, P3, refp, P0);
    // 6) src2 = sampled @ W_out + b_out + src
    gemm64<0, 1><<<dim3(256 / 64, M / 64), 256, 0, stream>>>(P0, Wo, bo, src, P1, M, 256, 256);
    // 7) h0 = LN2(src2)
    ln_kernel<<<M / 4, 256, 0, stream>>>(P1, n2g, n2b, nullptr, P2);
    // 8/9) FFN in 8 row-chunks to bound workspace: h1 = gelu(h0@Wf1+bf1); out = h1@Wf2+bf2+src2
    const int Mc = M / 8;              // 5440
    for (int c = 0; c < 8; c++) {
        const float* h0c  = P2 + (size_t)c * Mc * 256;
        const float* s2c  = P1 + (size_t)c * Mc * 256;
        float*       outc = out + (size_t)c * Mc * 256;
        gemm64<1, 0><<<dim3(1024 / 64, Mc / 64), 256, 0, stream>>>(h0c, Wf1, bf1, nullptr, P4, Mc, 1024, 256);
        gemm64<0, 1><<<dim3(256 / 64, Mc / 64), 256, 0, stream>>>(P4, Wf2, bf2, s2c, outc, Mc, 256, 1024);
    }
}

// Round 2
// 1428.558 us; speedup vs baseline: 1.2758x; 1.2758x over previous
//
#include <hip/hip_runtime.h>
#include <hip/hip_bf16.h>
#include <math.h>

// Problem constants (from reference)
#define LEN_TOT 21760
#define BATCH 2
#define MROWS (BATCH * LEN_TOT)   // 43520
#define DMODEL 256
#define DFFN 1024

// ---------------------------------------------------------------------------
// LayerNorm (+ optional additive term, e.g. pos): y = LN(x)*g + b [+ add]
// One 64-lane wave per 256-float row; 4 rows per 256-thread block.
// ---------------------------------------------------------------------------
__global__ __launch_bounds__(256) void ln_kernel(
    const float* __restrict__ x, const float* __restrict__ g,
    const float* __restrict__ bb, const float* __restrict__ addv,
    float* __restrict__ y)
{
    int row  = blockIdx.x * 4 + (threadIdx.x >> 6);
    int lane = threadIdx.x & 63;
    size_t base = (size_t)row * DMODEL + lane * 4;
    float4 v = *(const float4*)(x + base);

    float s = v.x + v.y + v.z + v.w;
    #pragma unroll
    for (int o = 32; o; o >>= 1) s += __shfl_xor(s, o, 64);
    float mu = s * (1.0f / 256.0f);

    float d0 = v.x - mu, d1 = v.y - mu, d2 = v.z - mu, d3 = v.w - mu;
    float vs = d0*d0 + d1*d1 + d2*d2 + d3*d3;
    #pragma unroll
    for (int o = 32; o; o >>= 1) vs += __shfl_xor(vs, o, 64);
    float rstd = rsqrtf(vs * (1.0f / 256.0f) + 1e-5f);

    float4 gv = *(const float4*)(g  + lane * 4);
    float4 bv = *(const float4*)(bb + lane * 4);
    float4 o;
    o.x = d0 * rstd * gv.x + bv.x;
    o.y = d1 * rstd * gv.y + bv.y;
    o.z = d2 * rstd * gv.z + bv.z;
    o.w = d3 * rstd * gv.w + bv.w;
    if (addv) {
        float4 av = *(const float4*)(addv + base);
        o.x += av.x; o.y += av.y; o.z += av.z; o.w += av.w;
    }
    *(float4*)(y + base) = o;
}

// ---------------------------------------------------------------------------
// fp32 tiled GEMM: C[M,N] = act(A[M,K] @ W[K,N] + bias) [+ res]
// BM=128, BN=128, BK=16; 256 threads; each thread 8x8 outputs.
// Requires M%128==0, N%128==0, K%16==0.
// Inner step per wave: 64 v_fma (128 cyc) vs 4 ds_read_b128 (~48 cyc) -> FMA-bound.
// ---------------------------------------------------------------------------
template<int GELU_ACT, int HAS_RES>
__global__ __launch_bounds__(256) void gemm128(
    const float* __restrict__ A, const float* __restrict__ Wm,
    const float* __restrict__ bias, const float* __restrict__ res,
    float* __restrict__ C, int M, int N, int K)
{
    constexpr int BM = 128, BN = 128, BK = 16;
    __shared__ float As[BK][BM + 4];
    __shared__ float Bs[BK][BN + 4];

    const int tid = threadIdx.x;
    const int tx = tid & 15, ty = tid >> 4;       // 16x16 thread grid, 8x8 each
    const int m0 = blockIdx.y * BM, n0 = blockIdx.x * BN;

    float acc[8][8];
    #pragma unroll
    for (int i = 0; i < 8; i++)
        #pragma unroll
        for (int j = 0; j < 8; j++) acc[i][j] = 0.0f;

    const int ar = tid >> 2;          // 0..63 (A tile row, +64 for second)
    const int ac = (tid & 3) << 2;    // 0,4,8,12
    const int br = tid >> 5;          // 0..7  (W tile row, +8 for second)
    const int bc = (tid & 31) << 2;   // 0..124

    for (int k0 = 0; k0 < K; k0 += BK) {
        float4 a0 = *(const float4*)(A + (size_t)(m0 + ar) * K + k0 + ac);
        float4 a1 = *(const float4*)(A + (size_t)(m0 + ar + 64) * K + k0 + ac);
        float4 b0 = *(const float4*)(Wm + (size_t)(k0 + br) * N + n0 + bc);
        float4 b1 = *(const float4*)(Wm + (size_t)(k0 + br + 8) * N + n0 + bc);
        As[ac + 0][ar] = a0.x; As[ac + 1][ar] = a0.y;
        As[ac + 2][ar] = a0.z; As[ac + 3][ar] = a0.w;
        As[ac + 0][ar + 64] = a1.x; As[ac + 1][ar + 64] = a1.y;
        As[ac + 2][ar + 64] = a1.z; As[ac + 3][ar + 64] = a1.w;
        *(float4*)&Bs[br][bc]     = b0;
        *(float4*)&Bs[br + 8][bc] = b1;
        __syncthreads();

        #pragma unroll
        for (int k = 0; k < BK; k++) {
            float4 aA = *(const float4*)&As[k][ty << 3];
            float4 aB = *(const float4*)&As[k][(ty << 3) + 4];
            float4 bA = *(const float4*)&Bs[k][tx << 3];
            float4 bB = *(const float4*)&Bs[k][(tx << 3) + 4];
            float av[8] = {aA.x, aA.y, aA.z, aA.w, aB.x, aB.y, aB.z, aB.w};
            float bv[8] = {bA.x, bA.y, bA.z, bA.w, bB.x, bB.y, bB.z, bB.w};
            #pragma unroll
            for (int i = 0; i < 8; i++)
                #pragma unroll
                for (int j = 0; j < 8; j++)
                    acc[i][j] = fmaf(av[i], bv[j], acc[i][j]);
        }
        __syncthreads();
    }

    float4 bb0 = *(const float4*)(bias + n0 + (tx << 3));
    float4 bb1 = *(const float4*)(bias + n0 + (tx << 3) + 4);
    #pragma unroll
    for (int i = 0; i < 8; i++) {
        int row = m0 + (ty << 3) + i;
        size_t cbase = (size_t)row * N + n0 + (tx << 3);
        float o[8];
        o[0] = acc[i][0] + bb0.x; o[1] = acc[i][1] + bb0.y;
        o[2] = acc[i][2] + bb0.z; o[3] = acc[i][3] + bb0.w;
        o[4] = acc[i][4] + bb1.x; o[5] = acc[i][5] + bb1.y;
        o[6] = acc[i][6] + bb1.z; o[7] = acc[i][7] + bb1.w;
        if (GELU_ACT) {
            const float inv_sqrt2 = 0.7071067811865476f;
            #pragma unroll
            for (int j = 0; j < 8; j++)
                o[j] = 0.5f * o[j] * (1.0f + erff(o[j] * inv_sqrt2));
        }
        if (HAS_RES) {
            float4 r0 = *(const float4*)(res + cbase);
            float4 r1 = *(const float4*)(res + cbase + 4);
            o[0] += r0.x; o[1] += r0.y; o[2] += r0.z; o[3] += r0.w;
            o[4] += r1.x; o[5] += r1.y; o[6] += r1.z; o[7] += r1.w;
        }
        float4 s0 = {o[0], o[1], o[2], o[3]};
        float4 s1 = {o[4], o[5], o[6], o[7]};
        *(float4*)(C + cbase)     = s0;
        *(float4*)(C + cbase + 4) = s1;
    }
}

// ---------------------------------------------------------------------------
// Fused softmax + multi-scale deformable bilinear sampling, v2.
// One 32-lane subgroup per (b, q, head); lane = channel d (HEAD_DIM=32).
// Lane i (mirrored i+16) computes sample i's metadata ONCE (clamped corner
// offsets + validity/prob-folded bilinear weights); inner loop is 8 shfl
// broadcasts + 4 (add+load+fma) per sample.
// ---------------------------------------------------------------------------
__global__ __launch_bounds__(256) void msdeform_kernel(
    const float* __restrict__ value, const float* __restrict__ offs,
    const float* __restrict__ logits, const float* __restrict__ refp,
    float* __restrict__ out)
{
    int gid = blockIdx.x * 8 + (threadIdx.x >> 5);  // (b*LEN + q)*8 + m
    int d   = threadIdx.x & 31;
    int bq  = gid >> 3;
    int m   = gid & 7;
    int b   = (bq >= LEN_TOT) ? 1 : 0;

    int i = d & 15;                 // sample index (lanes 16-31 mirror 0-15)
    // ---- fused softmax over the 16 (level,point) logits ----
    float logit = logits[(size_t)gid * 16 + i];
    float mx = logit;
    #pragma unroll
    for (int o = 8; o; o >>= 1) mx = fmaxf(mx, __shfl_xor(mx, o, 16));
    float e = __expf(logit - mx);
    float se = e;
    #pragma unroll
    for (int o = 8; o; o >>= 1) se += __shfl_xor(se, o, 16);
    float prob = e / se;

    // ---- per-sample metadata (computed once per sample, on its lane) ----
    int lvl = i >> 2;
    int Wl  = 128 >> lvl;
    float Wf = (float)Wl;
    const int ST_[4] = {0, 16384, 20480, 21504};

    float2 off2 = ((const float2*)offs)[(size_t)gid * 16 + i];
    float2 ref2 = ((const float2*)refp)[(size_t)bq * 4 + lvl];
    // loc*W - 0.5 with normalizer == (W,H):  ref*W + off - 0.5
    float xs = fmaf(ref2.x, Wf, off2.x) - 0.5f;
    float ys = fmaf(ref2.y, Wf, off2.y) - 0.5f;
    float xf = floorf(xs), yf = floorf(ys);
    int x0 = (int)xf, y0 = (int)yf;
    float wx = xs - xf, wy = ys - yf;
    float wx1 = 1.0f - wx, wy1 = 1.0f - wy;

    bool vx0 = (x0 >= 0) & (x0 < Wl);
    bool vx1 = (x0 + 1 >= 0) & (x0 + 1 < Wl);
    bool vy0 = (y0 >= 0) & (y0 < Wl);
    bool vy1 = (y0 + 1 >= 0) & (y0 + 1 < Wl);
    int cx0 = min(max(x0, 0), Wl - 1);
    int cx1 = min(max(x0 + 1, 0), Wl - 1);
    int cy0 = min(max(y0, 0), Wl - 1);
    int cy1 = min(max(y0 + 1, 0), Wl - 1);

    int base = b * LEN_TOT + ST_[lvl];
    int i00 = (base + cy0 * Wl + cx0) * 256 + m * 32;
    int i01 = (base + cy0 * Wl + cx1) * 256 + m * 32;
    int i10 = (base + cy1 * Wl + cx0) * 256 + m * 32;
    int i11 = (base + cy1 * Wl + cx1) * 256 + m * 32;
    float w00 = (vx0 && vy0) ? prob * wx1 * wy1 : 0.0f;
    float w01 = (vx1 && vy0) ? prob * wx  * wy1 : 0.0f;
    float w10 = (vx0 && vy1) ? prob * wx1 * wy  : 0.0f;
    float w11 = (vx1 && vy1) ? prob * wx  * wy  : 0.0f;

    // ---- gather loop: all 32 lanes, lane d = channel ----
    float acc = 0.0f;
    #pragma unroll
    for (int s = 0; s < 16; s++) {
        int   a00 = __shfl(i00, s, 32); float c00 = __shfl(w00, s, 32);
        int   a01 = __shfl(i01, s, 32); float c01 = __shfl(w01, s, 32);
        int   a10 = __shfl(i10, s, 32); float c10 = __shfl(w10, s, 32);
        int   a11 = __shfl(i11, s, 32); float c11 = __shfl(w11, s, 32);
        acc = fmaf(c00, value[a00 + d], acc);
        acc = fmaf(c01, value[a01 + d], acc);
        acc = fmaf(c10, value[a10 + d], acc);
        acc = fmaf(c11, value[a11 + d], acc);
    }
    out[(size_t)gid * 32 + d] = acc;
}

// ---------------------------------------------------------------------------
// kernel_launch
// ---------------------------------------------------------------------------
extern "C" void kernel_launch(void* const* d_in, const int* in_sizes, int n_in,
                              void* d_out, int out_size, void* d_ws, size_t ws_size,
                              hipStream_t stream)
{
    const float* src  = (const float*)d_in[0];
    const float* pos  = (const float*)d_in[1];
    const float* refp = (const float*)d_in[2];
    const float* n1g = (const float*)d_in[5];
    const float* n1b = (const float*)d_in[6];
    const float* n2g = (const float*)d_in[7];
    const float* n2b = (const float*)d_in[8];
    const float* Wv  = (const float*)d_in[9];
    const float* bv  = (const float*)d_in[10];
    const float* Wof = (const float*)d_in[11];
    const float* bof = (const float*)d_in[12];
    const float* Wat = (const float*)d_in[13];
    const float* bat = (const float*)d_in[14];
    const float* Wo  = (const float*)d_in[15];
    const float* bo  = (const float*)d_in[16];
    const float* Wf1 = (const float*)d_in[17];
    const float* bf1 = (const float*)d_in[18];
    const float* Wf2 = (const float*)d_in[19];
    const float* bf2 = (const float*)d_in[20];
    float* out = (float*)d_out;

    float* ws = (float*)d_ws;
    const int M = MROWS;               // 43520
    float* P0 = ws;                                  // q -> sampled      [M,256]
    float* P1 = P0 + (size_t)M * 256;                // value -> src2     [M,256]
    float* P2 = P1 + (size_t)M * 256;                // offsets -> h0(LN2)[M,256]
    float* P3 = P2 + (size_t)M * 256;                // logits [M,128]; FFN hidden chunk overlays (P3 dead by then)
    float* P4 = P3;                                  // FFN hidden chunk [Mc,1024]

    // 1) q = LN1(src) + pos
    ln_kernel<<<M / 4, 256, 0, stream>>>(src, n1g, n1b, pos, P0);
    // 2) value = src @ W_value + b_value  (un-normed src, per reference)
    gemm128<0, 0><<<dim3(256 / 128, M / 128), 256, 0, stream>>>(src, Wv, bv, nullptr, P1, M, 256, 256);
    // 3) offsets = q @ W_off + b_off
    gemm128<0, 0><<<dim3(256 / 128, M / 128), 256, 0, stream>>>(P0, Wof, bof, nullptr, P2, M, 256, 256);
    // 4) attn logits = q @ W_attn + b_attn
    gemm128<0, 0><<<dim3(128 / 128, M / 128), 256, 0, stream>>>(P0, Wat, bat, nullptr, P3, M, 128, 256);
    // 5) fused softmax + deformable sampling -> sampled (overwrites q in P0)
    msdeform_kernel<<<M, 256, 0, stream>>>(P1, P2, P3, refp, P0);
    // 6) src2 = sampled @ W_out + b_out + src
    gemm128<0, 1><<<dim3(256 / 128, M / 128), 256, 0, stream>>>(P0, Wo, bo, src, P1, M, 256, 256);
    // 7) h0 = LN2(src2)
    ln_kernel<<<M / 4, 256, 0, stream>>>(P1, n2g, n2b, nullptr, P2);
    // 8/9) FFN in 2 row-chunks: h1 = gelu(h0@Wf1+bf1); out = h1@Wf2+bf2+src2
    const int Mc = M / 2;              // 21760, divisible by 128
    for (int c = 0; c < 2; c++) {
        const float* h0c  = P2 + (size_t)c * Mc * 256;
        const float* s2c  = P1 + (size_t)c * Mc * 256;
        float*       outc = out + (size_t)c * Mc * 256;
        gemm128<1, 0><<<dim3(1024 / 128, Mc / 128), 256, 0, stream>>>(h0c, Wf1, bf1, nullptr, P4, Mc, 1024, 256);
        gemm128<0, 1><<<dim3(256 / 128, Mc / 128), 256, 0, stream>>>(P4, Wf2, bf2, s2c, outc, Mc, 256, 1024);
    }
}

// Round 4
// 516.975 us; speedup vs baseline: 3.5255x; 2.7633x over previous
//
#include <hip/hip_runtime.h>
#include <hip/hip_bf16.h>
#include <math.h>

// Problem constants (from reference)
#define LEN_TOT 21760
#define BATCH 2
#define MROWS (BATCH * LEN_TOT)   // 43520
#define DMODEL 256
#define DFFN 1024

typedef unsigned short ushort_t;
typedef __attribute__((ext_vector_type(8))) short short8;
typedef __attribute__((ext_vector_type(4))) float floatx4;

// fp32 -> bf16 raw bits, round-to-nearest-even
__device__ __forceinline__ ushort_t f2b(float f) {
    unsigned u = __float_as_uint(f);
    unsigned r = (u + 0x7FFFu + ((u >> 16) & 1u)) >> 16;
    return (ushort_t)r;
}

// ---------------------------------------------------------------------------
// Fused weight transpose + fp32->bf16 convert: W[K][N] f32 -> WT[N][K] bf16.
// One 32x32 tile per block; 6 weights in one launch.
// ---------------------------------------------------------------------------
struct TP {
    const float* s[6];
    ushort_t*    d[6];
    int K[6];
    int N[6];
    int start[7];
};

__global__ __launch_bounds__(256) void transpose_convert(TP tp) {
    __shared__ float tile[32][33];
    int blk = blockIdx.x;
    int seg = 0;
    while (seg < 5 && blk >= tp.start[seg + 1]) seg++;
    int local = blk - tp.start[seg];
    int K = tp.K[seg], N = tp.N[seg];
    int tn = N >> 5;
    int k0 = (local / tn) << 5, n0 = (local % tn) << 5;
    int r = threadIdx.x >> 5, c = threadIdx.x & 31;
    const float* src = tp.s[seg];
    #pragma unroll
    for (int rr = r; rr < 32; rr += 8)
        tile[rr][c] = src[(size_t)(k0 + rr) * N + n0 + c];
    __syncthreads();
    ushort_t* dst = tp.d[seg];
    #pragma unroll
    for (int rr = r; rr < 32; rr += 8)
        dst[(size_t)(n0 + rr) * K + k0 + c] = f2b(tile[c][rr]);
}

// ---------------------------------------------------------------------------
// LayerNorm (+ optional pos add) -> bf16 output; optionally also emits
// bf16 copy of the raw input (for the un-normed value path).
// One 64-lane wave per 256-float row; 4 rows per block.
// ---------------------------------------------------------------------------
__global__ __launch_bounds__(256) void ln_dual_kernel(
    const float* __restrict__ x, const float* __restrict__ g,
    const float* __restrict__ bb, const float* __restrict__ addv,
    ushort_t* __restrict__ y_bf, ushort_t* __restrict__ x_bf)
{
    int row  = blockIdx.x * 4 + (threadIdx.x >> 6);
    int lane = threadIdx.x & 63;
    size_t base = (size_t)row * DMODEL + lane * 4;
    float4 v = *(const float4*)(x + base);

    float s = v.x + v.y + v.z + v.w;
    #pragma unroll
    for (int o = 32; o; o >>= 1) s += __shfl_xor(s, o, 64);
    float mu = s * (1.0f / 256.0f);

    float d0 = v.x - mu, d1 = v.y - mu, d2 = v.z - mu, d3 = v.w - mu;
    float vs = d0*d0 + d1*d1 + d2*d2 + d3*d3;
    #pragma unroll
    for (int o = 32; o; o >>= 1) vs += __shfl_xor(vs, o, 64);
    float rstd = rsqrtf(vs * (1.0f / 256.0f) + 1e-5f);

    float4 gv = *(const float4*)(g  + lane * 4);
    float4 bv = *(const float4*)(bb + lane * 4);
    float o0 = d0 * rstd * gv.x + bv.x;
    float o1 = d1 * rstd * gv.y + bv.y;
    float o2 = d2 * rstd * gv.z + bv.z;
    float o3 = d3 * rstd * gv.w + bv.w;
    if (addv) {
        float4 av = *(const float4*)(addv + base);
        o0 += av.x; o1 += av.y; o2 += av.z; o3 += av.w;
    }
    ushort4 ob = {f2b(o0), f2b(o1), f2b(o2), f2b(o3)};
    *(ushort4*)(y_bf + base) = ob;
    if (x_bf) {
        ushort4 xb = {f2b(v.x), f2b(v.y), f2b(v.z), f2b(v.w)};
        *(ushort4*)(x_bf + base) = xb;
    }
}

// ---------------------------------------------------------------------------
// bf16 MFMA GEMM: C[M,N] = act(A[M,K] @ B[K,N] + bias) [+ res]
// A: [M][K] bf16 row-major. Bt: [N][K] bf16 (pre-transposed weight).
// BM=BN=128, BK=32; 256 threads = 4 waves, each wave 4x4 16x16 tiles.
// fp32 accumulate; epilogue fp32. OUT_BF16: store bf16 instead of fp32.
// ---------------------------------------------------------------------------
template<int GELU_ACT, int HAS_RES, int OUT_BF16>
__global__ __launch_bounds__(256) void gemm_mfma(
    const ushort_t* __restrict__ A, const ushort_t* __restrict__ Bt,
    const float* __restrict__ bias, const float* __restrict__ res,
    float* __restrict__ C, ushort_t* __restrict__ Cbf,
    int M, int N, int K)
{
    constexpr int BM = 128, BK = 32;
    constexpr int LDA = BK + 8;   // 40 shorts = 80 B rows (16B-aligned, bank-spread)
    __shared__ __align__(16) ushort_t As[BM * LDA];
    __shared__ __align__(16) ushort_t Bs[BM * LDA];

    const int tid  = threadIdx.x;
    const int wave = tid >> 6;
    const int lane = tid & 63;
    const int wm = (wave & 1) * 64;
    const int wn = (wave >> 1) * 64;
    const int ml = lane & 15;      // m (A) / n (B) / col (D)
    const int quad = lane >> 4;    // k-block for A/B; row-block for D
    const int m0 = blockIdx.y * BM, n0 = blockIdx.x * BM;

    floatx4 acc[4][4] = {};

    for (int k0 = 0; k0 < K; k0 += BK) {
        #pragma unroll
        for (int it = 0; it < 2; it++) {
            int idx = tid + it * 256;      // 0..511
            int r = idx >> 2, seg = idx & 3;
            *(short8*)(As + r * LDA + seg * 8) =
                *(const short8*)(A + (size_t)(m0 + r) * K + k0 + seg * 8);
            *(short8*)(Bs + r * LDA + seg * 8) =
                *(const short8*)(Bt + (size_t)(n0 + r) * K + k0 + seg * 8);
        }
        __syncthreads();

        short8 af[4], bfr[4];
        #pragma unroll
        for (int i = 0; i < 4; i++)
            af[i] = *(const short8*)(As + (wm + i * 16 + ml) * LDA + quad * 8);
        #pragma unroll
        for (int j = 0; j < 4; j++)
            bfr[j] = *(const short8*)(Bs + (wn + j * 16 + ml) * LDA + quad * 8);
        #pragma unroll
        for (int i = 0; i < 4; i++)
            #pragma unroll
            for (int j = 0; j < 4; j++)
                acc[i][j] = __builtin_amdgcn_mfma_f32_16x16x32_bf16(
                    af[i], bfr[j], acc[i][j], 0, 0, 0);
        __syncthreads();
    }

    // Epilogue. D layout: col = lane&15, row = quad*4 + reg.
    #pragma unroll
    for (int j = 0; j < 4; j++) {
        int col = n0 + wn + j * 16 + ml;
        float bc = bias[col];
        #pragma unroll
        for (int i = 0; i < 4; i++) {
            int row = m0 + wm + i * 16 + quad * 4;
            #pragma unroll
            for (int r = 0; r < 4; r++) {
                float v = acc[i][j][r] + bc;
                if (GELU_ACT) {
                    v = 0.5f * v * (1.0f + erff(v * 0.7071067811865476f));
                }
                if (HAS_RES) v += res[(size_t)(row + r) * N + col];
                if (OUT_BF16) Cbf[(size_t)(row + r) * N + col] = f2b(v);
                else          C[(size_t)(row + r) * N + col] = v;
            }
        }
    }
}

// ---------------------------------------------------------------------------
// Fused softmax + multi-scale deformable bilinear sampling, v3.
// 32-lane subgroup per (b,q,head). Metadata: lane i computes sample i's
// 4 clamped corner indices + prob/validity-folded weights. Gather phase:
// lane = (corner cl = l>>3, channel-quad d4 = l&7); per sample: 2 shuffle
// broadcasts + 1 float4 load + 4 FMA. Final xor-shuffle reduce over corners.
// Output written as bf16 (feeds out-proj MFMA GEMM).
// ---------------------------------------------------------------------------
__global__ __launch_bounds__(256) void msdeform_kernel(
    const float* __restrict__ value, const float* __restrict__ offs,
    const float* __restrict__ logits, const float* __restrict__ refp,
    ushort_t* __restrict__ out_bf)
{
    int gid = blockIdx.x * 8 + (threadIdx.x >> 5);  // (b*LEN + q)*8 + m
    int l   = threadIdx.x & 31;
    int bq  = gid >> 3;
    int m   = gid & 7;
    int b   = (bq >= LEN_TOT) ? 1 : 0;

    int i = l & 15;                 // sample index (lanes 16-31 mirror 0-15)
    // ---- softmax over the 16 (level,point) logits ----
    float logit = logits[(size_t)gid * 16 + i];
    float mx = logit;
    #pragma unroll
    for (int o = 8; o; o >>= 1) mx = fmaxf(mx, __shfl_xor(mx, o, 32));
    float e = __expf(logit - mx);
    float se = e;
    #pragma unroll
    for (int o = 8; o; o >>= 1) se += __shfl_xor(se, o, 32);
    float prob = e / se;

    // ---- per-sample metadata ----
    int lvl = i >> 2;
    int Wl  = 128 >> lvl;
    float Wf = (float)Wl;
    const int ST_[4] = {0, 16384, 20480, 21504};

    float2 off2 = ((const float2*)offs)[(size_t)gid * 16 + i];
    float2 ref2 = ((const float2*)refp)[(size_t)bq * 4 + lvl];
    float xs = fmaf(ref2.x, Wf, off2.x) - 0.5f;
    float ys = fmaf(ref2.y, Wf, off2.y) - 0.5f;
    float xf = floorf(xs), yf = floorf(ys);
    int x0 = (int)xf, y0 = (int)yf;
    float wx = xs - xf, wy = ys - yf;
    float wx1 = 1.0f - wx, wy1 = 1.0f - wy;

    bool vx0 = (x0 >= 0) & (x0 < Wl);
    bool vx1 = (x0 + 1 >= 0) & (x0 + 1 < Wl);
    bool vy0 = (y0 >= 0) & (y0 < Wl);
    bool vy1 = (y0 + 1 >= 0) & (y0 + 1 < Wl);
    int cx0 = min(max(x0, 0), Wl - 1);
    int cx1 = min(max(x0 + 1, 0), Wl - 1);
    int cy0 = min(max(y0, 0), Wl - 1);
    int cy1 = min(max(y0 + 1, 0), Wl - 1);

    int vbase = b * LEN_TOT + ST_[lvl];
    int i00 = (vbase + cy0 * Wl + cx0) * 256 + m * 32;
    int i01 = (vbase + cy0 * Wl + cx1) * 256 + m * 32;
    int i10 = (vbase + cy1 * Wl + cx0) * 256 + m * 32;
    int i11 = (vbase + cy1 * Wl + cx1) * 256 + m * 32;
    float w00 = (vx0 && vy0) ? prob * wx1 * wy1 : 0.0f;
    float w01 = (vx1 && vy0) ? prob * wx  * wy1 : 0.0f;
    float w10 = (vx0 && vy1) ? prob * wx1 * wy  : 0.0f;
    float w11 = (vx1 && vy1) ? prob * wx  * wy  : 0.0f;

    // ---- redistribute: lane l holds (sample l>>2, corner l&3) for varA
    //      and (sample (l>>2)+8, corner l&3) for varB ----
    int sA = l >> 2;
    int cA = l & 3;
    int t0 = __shfl(i00, sA, 32), t1 = __shfl(i01, sA, 32);
    int t2 = __shfl(i10, sA, 32), t3 = __shfl(i11, sA, 32);
    int addrA = (cA == 0) ? t0 : (cA == 1) ? t1 : (cA == 2) ? t2 : t3;
    float u0 = __shfl(w00, sA, 32), u1 = __shfl(w01, sA, 32);
    float u2 = __shfl(w10, sA, 32), u3 = __shfl(w11, sA, 32);
    float wA = (cA == 0) ? u0 : (cA == 1) ? u1 : (cA == 2) ? u2 : u3;
    t0 = __shfl(i00, sA + 8, 32); t1 = __shfl(i01, sA + 8, 32);
    t2 = __shfl(i10, sA + 8, 32); t3 = __shfl(i11, sA + 8, 32);
    int addrB = (cA == 0) ? t0 : (cA == 1) ? t1 : (cA == 2) ? t2 : t3;
    u0 = __shfl(w00, sA + 8, 32); u1 = __shfl(w01, sA + 8, 32);
    u2 = __shfl(w10, sA + 8, 32); u3 = __shfl(w11, sA + 8, 32);
    float wB = (cA == 0) ? u0 : (cA == 1) ? u1 : (cA == 2) ? u2 : u3;

    // ---- gather: lane = (corner cl, channel-quad d4) ----
    int cl = l >> 3;
    int d4 = l & 7;
    float ax = 0.0f, ay = 0.0f, az = 0.0f, aw = 0.0f;
    #pragma unroll
    for (int s = 0; s < 8; s++) {
        int   a = __shfl(addrA, s * 4 + cl, 32);
        float w = __shfl(wA,    s * 4 + cl, 32);
        float4 v = *(const float4*)(value + a + (d4 << 2));
        ax = fmaf(w, v.x, ax); ay = fmaf(w, v.y, ay);
        az = fmaf(w, v.z, az); aw = fmaf(w, v.w, aw);
    }
    #pragma unroll
    for (int s = 0; s < 8; s++) {
        int   a = __shfl(addrB, s * 4 + cl, 32);
        float w = __shfl(wB,    s * 4 + cl, 32);
        float4 v = *(const float4*)(value + a + (d4 << 2));
        ax = fmaf(w, v.x, ax); ay = fmaf(w, v.y, ay);
        az = fmaf(w, v.z, az); aw = fmaf(w, v.w, aw);
    }
    // reduce over the 4 corners (lanes xor 8, xor 16)
    ax += __shfl_xor(ax, 8, 32);  ay += __shfl_xor(ay, 8, 32);
    az += __shfl_xor(az, 8, 32);  aw += __shfl_xor(aw, 8, 32);
    ax += __shfl_xor(ax, 16, 32); ay += __shfl_xor(ay, 16, 32);
    az += __shfl_xor(az, 16, 32); aw += __shfl_xor(aw, 16, 32);

    if (l < 8) {
        ushort4 o = {f2b(ax), f2b(ay), f2b(az), f2b(aw)};
        *(ushort4*)(out_bf + (size_t)gid * 32 + (d4 << 2)) = o;
    }
}

// ---------------------------------------------------------------------------
// kernel_launch
//
// Workspace layout (no aliasing hazards; h1_bf EXACTLY overlays the three
// regions that are dead by step 8):
//   [0)            q_bf   [M,256] bf16  -> reused as h0_bf      (22.28 MB)
//   [A)            value  [M,256] f32   -> reused as src2       (44.56 MB)
//   [B)            src_bf [M,256] bf16  -> sampled; h1_bf base  (22.28 MB)
//   [C)            offs   [M,256] f32   (dead after step 5)     (44.56 MB)
//   [D)            logits [M,128] f32   (dead after step 5)     (22.28 MB)
//   [E)            transposed weights (bf16)                    ( 1.51 MB)
//   h1_bf = [B, E) = 89.13 MB == M*1024*2 exactly. Total ~157.5 MB.
// ---------------------------------------------------------------------------
extern "C" void kernel_launch(void* const* d_in, const int* in_sizes, int n_in,
                              void* d_out, int out_size, void* d_ws, size_t ws_size,
                              hipStream_t stream)
{
    const float* src  = (const float*)d_in[0];
    const float* pos  = (const float*)d_in[1];
    const float* refp = (const float*)d_in[2];
    const float* n1g = (const float*)d_in[5];
    const float* n1b = (const float*)d_in[6];
    const float* n2g = (const float*)d_in[7];
    const float* n2b = (const float*)d_in[8];
    const float* Wv  = (const float*)d_in[9];
    const float* bv  = (const float*)d_in[10];
    const float* Wof = (const float*)d_in[11];
    const float* bof = (const float*)d_in[12];
    const float* Wat = (const float*)d_in[13];
    const float* bat = (const float*)d_in[14];
    const float* Wo  = (const float*)d_in[15];
    const float* bo  = (const float*)d_in[16];
    const float* Wf1 = (const float*)d_in[17];
    const float* bf1 = (const float*)d_in[18];
    const float* Wf2 = (const float*)d_in[19];
    const float* bf2 = (const float*)d_in[20];
    float* out = (float*)d_out;

    char* ws = (char*)d_ws;
    const int M = MROWS;               // 43520
    const size_t SZ_BF = (size_t)M * 256 * 2;   // 22,282,240
    const size_t SZ_F  = (size_t)M * 256 * 4;   // 44,564,480

    ushort_t* q_bf    = (ushort_t*)(ws);                              // [M,256] bf16
    float*    value   = (float*)   (ws + SZ_BF);                      // [M,256] f32
    ushort_t* src_bf  = (ushort_t*)(ws + SZ_BF + SZ_F);               // [M,256] bf16
    float*    offsb   = (float*)   (ws + 2 * SZ_BF + SZ_F);           // [M,256] f32
    float*    logitsb = (float*)   (ws + 2 * SZ_BF + 2 * SZ_F);       // [M,128] f32
    ushort_t* h0_bf   = q_bf;
    ushort_t* sampled = src_bf;
    float*    src2    = value;
    ushort_t* h1_bf   = src_bf;   // [M,1024] bf16, spans src_bf+offs+logits exactly
    char* wtp = ws + 2 * SZ_BF + 2 * SZ_F + (size_t)M * 128 * 4;
    ushort_t* WvT  = (ushort_t*)(wtp);
    ushort_t* WofT = WvT  + 256 * 256;
    ushort_t* WatT = WofT + 256 * 256;
    ushort_t* WoT  = WatT + 256 * 128;
    ushort_t* Wf1T = WoT  + 256 * 256;
    ushort_t* Wf2T = Wf1T + 256 * 1024;

    // 0) transpose+convert all weights to [N][K] bf16
    TP tp;
    tp.s[0] = Wv;  tp.d[0] = WvT;  tp.K[0] = 256;  tp.N[0] = 256;
    tp.s[1] = Wof; tp.d[1] = WofT; tp.K[1] = 256;  tp.N[1] = 256;
    tp.s[2] = Wat; tp.d[2] = WatT; tp.K[2] = 256;  tp.N[2] = 128;
    tp.s[3] = Wo;  tp.d[3] = WoT;  tp.K[3] = 256;  tp.N[3] = 256;
    tp.s[4] = Wf1; tp.d[4] = Wf1T; tp.K[4] = 256;  tp.N[4] = 1024;
    tp.s[5] = Wf2; tp.d[5] = Wf2T; tp.K[5] = 1024; tp.N[5] = 256;
    tp.start[0] = 0;   tp.start[1] = 64;  tp.start[2] = 128;
    tp.start[3] = 160; tp.start[4] = 224; tp.start[5] = 480; tp.start[6] = 736;
    transpose_convert<<<736, 256, 0, stream>>>(tp);

    // 1) q_bf = bf16(LN1(src) + pos); src_bf = bf16(src)
    ln_dual_kernel<<<M / 4, 256, 0, stream>>>(src, n1g, n1b, pos, q_bf, src_bf);
    // 2) value = src_bf @ Wv + bv   (fp32 out)
    gemm_mfma<0, 0, 0><<<dim3(2, M / 128), 256, 0, stream>>>(
        src_bf, WvT, bv, nullptr, value, nullptr, M, 256, 256);
    // 3) offs = q_bf @ Wof + bof    (fp32 out)
    gemm_mfma<0, 0, 0><<<dim3(2, M / 128), 256, 0, stream>>>(
        q_bf, WofT, bof, nullptr, offsb, nullptr, M, 256, 256);
    // 4) logits = q_bf @ Wat + bat  (fp32 out)
    gemm_mfma<0, 0, 0><<<dim3(1, M / 128), 256, 0, stream>>>(
        q_bf, WatT, bat, nullptr, logitsb, nullptr, M, 128, 256);
    // 5) fused softmax + sampling -> sampled (bf16, overwrites src_bf; offs/logits dead after)
    msdeform_kernel<<<M, 256, 0, stream>>>(value, offsb, logitsb, refp, sampled);
    // 6) src2 = sampled @ Wo + bo + src  (fp32, overwrites value)
    gemm_mfma<0, 1, 0><<<dim3(2, M / 128), 256, 0, stream>>>(
        sampled, WoT, bo, src, src2, nullptr, M, 256, 256);
    // 7) h0_bf = bf16(LN2(src2))
    ln_dual_kernel<<<M / 4, 256, 0, stream>>>(src2, n2g, n2b, nullptr, h0_bf, nullptr);
    // 8) h1_bf = bf16(gelu(h0_bf @ Wf1 + bf1))  (h1 overlays sampled+offs+logits, all dead)
    gemm_mfma<1, 0, 1><<<dim3(8, M / 128), 256, 0, stream>>>(
        h0_bf, Wf1T, bf1, nullptr, nullptr, h1_bf, M, 1024, 256);
    // 9) out = h1_bf @ Wf2 + bf2 + src2  (fp32)
    gemm_mfma<0, 1, 0><<<dim3(2, M / 128), 256, 0, stream>>>(
        h1_bf, Wf2T, bf2, src2, out, nullptr, M, 256, 1024);
}

// Round 5
// 505.130 us; speedup vs baseline: 3.6081x; 1.0234x over previous
//
#include <hip/hip_runtime.h>
#include <hip/hip_bf16.h>
#include <math.h>

// Problem constants (from reference)
#define LEN_TOT 21760
#define BATCH 2
#define MROWS (BATCH * LEN_TOT)   // 43520
#define DMODEL 256
#define DFFN 1024

typedef unsigned short ushort_t;
typedef __attribute__((ext_vector_type(8))) short short8;
typedef __attribute__((ext_vector_type(4))) float floatx4;
typedef __attribute__((address_space(3))) ushort_t lds_us;
typedef __attribute__((address_space(1))) const ushort_t glb_us;

// fp32 -> bf16 raw bits, round-to-nearest-even
__device__ __forceinline__ ushort_t f2b(float f) {
    unsigned u = __float_as_uint(f);
    unsigned r = (u + 0x7FFFu + ((u >> 16) & 1u)) >> 16;
    return (ushort_t)r;
}

// ---------------------------------------------------------------------------
// Fused weight transpose + fp32->bf16 convert: W[K][N] f32 -> WT[N][K] bf16.
// ---------------------------------------------------------------------------
struct TP {
    const float* s[6];
    ushort_t*    d[6];
    int K[6];
    int N[6];
    int start[7];
};

__global__ __launch_bounds__(256) void transpose_convert(TP tp) {
    __shared__ float tile[32][33];
    int blk = blockIdx.x;
    int seg = 0;
    while (seg < 5 && blk >= tp.start[seg + 1]) seg++;
    int local = blk - tp.start[seg];
    int K = tp.K[seg], N = tp.N[seg];
    int tn = N >> 5;
    int k0 = (local / tn) << 5, n0 = (local % tn) << 5;
    int r = threadIdx.x >> 5, c = threadIdx.x & 31;
    const float* src = tp.s[seg];
    #pragma unroll
    for (int rr = r; rr < 32; rr += 8)
        tile[rr][c] = src[(size_t)(k0 + rr) * N + n0 + c];
    __syncthreads();
    ushort_t* dst = tp.d[seg];
    #pragma unroll
    for (int rr = r; rr < 32; rr += 8)
        dst[(size_t)(n0 + rr) * K + k0 + c] = f2b(tile[c][rr]);
}

// ---------------------------------------------------------------------------
// LayerNorm (+ optional pos add) -> bf16 output; optionally also emits
// bf16 copy of the raw input (for the un-normed value path).
// ---------------------------------------------------------------------------
__global__ __launch_bounds__(256) void ln_dual_kernel(
    const float* __restrict__ x, const float* __restrict__ g,
    const float* __restrict__ bb, const float* __restrict__ addv,
    ushort_t* __restrict__ y_bf, ushort_t* __restrict__ x_bf)
{
    int row  = blockIdx.x * 4 + (threadIdx.x >> 6);
    int lane = threadIdx.x & 63;
    size_t base = (size_t)row * DMODEL + lane * 4;
    float4 v = *(const float4*)(x + base);

    float s = v.x + v.y + v.z + v.w;
    #pragma unroll
    for (int o = 32; o; o >>= 1) s += __shfl_xor(s, o, 64);
    float mu = s * (1.0f / 256.0f);

    float d0 = v.x - mu, d1 = v.y - mu, d2 = v.z - mu, d3 = v.w - mu;
    float vs = d0*d0 + d1*d1 + d2*d2 + d3*d3;
    #pragma unroll
    for (int o = 32; o; o >>= 1) vs += __shfl_xor(vs, o, 64);
    float rstd = rsqrtf(vs * (1.0f / 256.0f) + 1e-5f);

    float4 gv = *(const float4*)(g  + lane * 4);
    float4 bv = *(const float4*)(bb + lane * 4);
    float o0 = d0 * rstd * gv.x + bv.x;
    float o1 = d1 * rstd * gv.y + bv.y;
    float o2 = d2 * rstd * gv.z + bv.z;
    float o3 = d3 * rstd * gv.w + bv.w;
    if (addv) {
        float4 av = *(const float4*)(addv + base);
        o0 += av.x; o1 += av.y; o2 += av.z; o3 += av.w;
    }
    ushort4 ob = {f2b(o0), f2b(o1), f2b(o2), f2b(o3)};
    *(ushort4*)(y_bf + base) = ob;
    if (x_bf) {
        ushort4 xb = {f2b(v.x), f2b(v.y), f2b(v.z), f2b(v.w)};
        *(ushort4*)(x_bf + base) = xb;
    }
}

// ---------------------------------------------------------------------------
// bf16 MFMA GEMM, m97-style staging: C[M,N] = act(A @ B + bias) [+ res]
// A: [M][K] bf16 row-major. Bt: [N][K] bf16 (pre-transposed weight).
// BM=BN=128, BK=32; 256 threads = 4 waves, each wave 4x4 16x16x32 tiles.
// Staging via global_load_lds width=16 into unpadded [128][32] LDS tiles
// (LDS dest = wave-uniform base + lane*16; offset(idx)=idx*16 satisfies it).
// OUT_BF16 path: wave-private LDS-staged epilogue -> dwordx4 stores.
// ---------------------------------------------------------------------------
template<int GELU_ACT, int HAS_RES, int OUT_BF16>
__global__ __launch_bounds__(256) void gemm_mfma(
    const ushort_t* __restrict__ A, const ushort_t* __restrict__ Bt,
    const float* __restrict__ bias, const float* __restrict__ res,
    float* __restrict__ C, ushort_t* __restrict__ Cbf,
    int M, int N, int K)
{
    constexpr int BM = 128, BK = 32;
    __shared__ __align__(16) ushort_t As[BM * BK];   // 8 KB
    __shared__ __align__(16) ushort_t Bs[BM * BK];   // 8 KB

    const int tid  = threadIdx.x;
    const int wave = tid >> 6;
    const int lane = tid & 63;
    const int wm = (wave & 1) * 64;
    const int wn = (wave >> 1) * 64;
    const int ml = lane & 15;      // m (A) / n (B) / col (D)
    const int quad = lane >> 4;    // k-block for A/B; row-block for D
    const int m0 = blockIdx.y * BM, n0 = blockIdx.x * BM;

    // staging map: idx in [0,512), row = idx>>2, seg = idx&3 (8 shorts each)
    // LDS offset(idx) = idx*16 B  ==  (wave,it)-uniform base + lane*16  ✓
    const int r0 = tid >> 2, s0 = tid & 3;
    const int r1 = (tid + 256) >> 2;       // s1 == s0

    floatx4 acc[4][4] = {};

    for (int k0 = 0; k0 < K; k0 += BK) {
        const ushort_t* gA0 = A  + (size_t)(m0 + r0) * K + k0 + s0 * 8;
        const ushort_t* gA1 = A  + (size_t)(m0 + r1) * K + k0 + s0 * 8;
        const ushort_t* gB0 = Bt + (size_t)(n0 + r0) * K + k0 + s0 * 8;
        const ushort_t* gB1 = Bt + (size_t)(n0 + r1) * K + k0 + s0 * 8;
        __builtin_amdgcn_global_load_lds((glb_us*)gA0, (lds_us*)(As + tid * 8),        16, 0, 0);
        __builtin_amdgcn_global_load_lds((glb_us*)gA1, (lds_us*)(As + (tid + 256) * 8),16, 0, 0);
        __builtin_amdgcn_global_load_lds((glb_us*)gB0, (lds_us*)(Bs + tid * 8),        16, 0, 0);
        __builtin_amdgcn_global_load_lds((glb_us*)gB1, (lds_us*)(Bs + (tid + 256) * 8),16, 0, 0);
        __syncthreads();

        short8 af[4], bfr[4];
        #pragma unroll
        for (int i = 0; i < 4; i++)
            af[i] = *(const short8*)(As + (wm + i * 16 + ml) * BK + quad * 8);
        #pragma unroll
        for (int j = 0; j < 4; j++)
            bfr[j] = *(const short8*)(Bs + (wn + j * 16 + ml) * BK + quad * 8);
        #pragma unroll
        for (int i = 0; i < 4; i++)
            #pragma unroll
            for (int j = 0; j < 4; j++)
                acc[i][j] = __builtin_amdgcn_mfma_f32_16x16x32_bf16(
                    af[i], bfr[j], acc[i][j], 0, 0, 0);
        __syncthreads();
    }

    // Epilogue. D layout: col = lane&15, row = quad*4 + reg.
    if (OUT_BF16) {
        // wave-private 4 KB region (spans As/Bs), ping-pong 2 KB per i-tile
        ushort_t* pool  = (wave < 2) ? As : Bs;
        ushort_t* wbase = pool + (wave & 1) * 2048;
        const int lr  = lane >> 2;   // 0..15 readback row
        const int sg  = lane & 3;    // readback 16B segment
        #pragma unroll
        for (int i = 0; i < 4; i++) {
            ushort_t* wbuf = wbase + (i & 1) * 1024;
            #pragma unroll
            for (int j = 0; j < 4; j++) {
                float bc = bias[n0 + wn + j * 16 + ml];
                #pragma unroll
                for (int r = 0; r < 4; r++) {
                    float v = acc[i][j][r] + bc;
                    if (GELU_ACT) v = 0.5f * v * (1.0f + erff(v * 0.7071067811865476f));
                    if (HAS_RES)
                        v += res[(size_t)(m0 + wm + i * 16 + quad * 4 + r) * N
                                 + n0 + wn + j * 16 + ml];
                    wbuf[(quad * 4 + r) * 64 + j * 16 + ml] = f2b(v);
                }
            }
            // intra-wave LDS write->read ordering (cross-lane dep)
            asm volatile("s_waitcnt lgkmcnt(0)" ::: "memory");
            #pragma unroll
            for (int h = 0; h < 2; h++) {
                short8 vv = *(const short8*)(wbuf + lr * 64 + (sg + 4 * h) * 8);
                *(short8*)(Cbf + (size_t)(m0 + wm + i * 16 + lr) * N
                                 + n0 + wn + (sg + 4 * h) * 8) = vv;
            }
        }
    } else {
        #pragma unroll
        for (int j = 0; j < 4; j++) {
            int col = n0 + wn + j * 16 + ml;
            float bc = bias[col];
            #pragma unroll
            for (int i = 0; i < 4; i++) {
                int row = m0 + wm + i * 16 + quad * 4;
                #pragma unroll
                for (int r = 0; r < 4; r++) {
                    float v = acc[i][j][r] + bc;
                    if (GELU_ACT) v = 0.5f * v * (1.0f + erff(v * 0.7071067811865476f));
                    if (HAS_RES) v += res[(size_t)(row + r) * N + col];
                    C[(size_t)(row + r) * N + col] = v;
                }
            }
        }
    }
}

// ---------------------------------------------------------------------------
// Fused softmax + multi-scale deformable bilinear sampling, v3.
// (unchanged from round 4 — correct; will re-evaluate once it tops profile)
// ---------------------------------------------------------------------------
__global__ __launch_bounds__(256) void msdeform_kernel(
    const float* __restrict__ value, const float* __restrict__ offs,
    const float* __restrict__ logits, const float* __restrict__ refp,
    ushort_t* __restrict__ out_bf)
{
    int gid = blockIdx.x * 8 + (threadIdx.x >> 5);  // (b*LEN + q)*8 + m
    int l   = threadIdx.x & 31;
    int bq  = gid >> 3;
    int m   = gid & 7;
    int b   = (bq >= LEN_TOT) ? 1 : 0;

    int i = l & 15;                 // sample index (lanes 16-31 mirror 0-15)
    float logit = logits[(size_t)gid * 16 + i];
    float mx = logit;
    #pragma unroll
    for (int o = 8; o; o >>= 1) mx = fmaxf(mx, __shfl_xor(mx, o, 32));
    float e = __expf(logit - mx);
    float se = e;
    #pragma unroll
    for (int o = 8; o; o >>= 1) se += __shfl_xor(se, o, 32);
    float prob = e / se;

    int lvl = i >> 2;
    int Wl  = 128 >> lvl;
    float Wf = (float)Wl;
    const int ST_[4] = {0, 16384, 20480, 21504};

    float2 off2 = ((const float2*)offs)[(size_t)gid * 16 + i];
    float2 ref2 = ((const float2*)refp)[(size_t)bq * 4 + lvl];
    float xs = fmaf(ref2.x, Wf, off2.x) - 0.5f;
    float ys = fmaf(ref2.y, Wf, off2.y) - 0.5f;
    float xf = floorf(xs), yf = floorf(ys);
    int x0 = (int)xf, y0 = (int)yf;
    float wx = xs - xf, wy = ys - yf;
    float wx1 = 1.0f - wx, wy1 = 1.0f - wy;

    bool vx0 = (x0 >= 0) & (x0 < Wl);
    bool vx1 = (x0 + 1 >= 0) & (x0 + 1 < Wl);
    bool vy0 = (y0 >= 0) & (y0 < Wl);
    bool vy1 = (y0 + 1 >= 0) & (y0 + 1 < Wl);
    int cx0 = min(max(x0, 0), Wl - 1);
    int cx1 = min(max(x0 + 1, 0), Wl - 1);
    int cy0 = min(max(y0, 0), Wl - 1);
    int cy1 = min(max(y0 + 1, 0), Wl - 1);

    int vbase = b * LEN_TOT + ST_[lvl];
    int i00 = (vbase + cy0 * Wl + cx0) * 256 + m * 32;
    int i01 = (vbase + cy0 * Wl + cx1) * 256 + m * 32;
    int i10 = (vbase + cy1 * Wl + cx0) * 256 + m * 32;
    int i11 = (vbase + cy1 * Wl + cx1) * 256 + m * 32;
    float w00 = (vx0 && vy0) ? prob * wx1 * wy1 : 0.0f;
    float w01 = (vx1 && vy0) ? prob * wx  * wy1 : 0.0f;
    float w10 = (vx0 && vy1) ? prob * wx1 * wy  : 0.0f;
    float w11 = (vx1 && vy1) ? prob * wx  * wy  : 0.0f;

    int sA = l >> 2;
    int cA = l & 3;
    int t0 = __shfl(i00, sA, 32), t1 = __shfl(i01, sA, 32);
    int t2 = __shfl(i10, sA, 32), t3 = __shfl(i11, sA, 32);
    int addrA = (cA == 0) ? t0 : (cA == 1) ? t1 : (cA == 2) ? t2 : t3;
    float u0 = __shfl(w00, sA, 32), u1 = __shfl(w01, sA, 32);
    float u2 = __shfl(w10, sA, 32), u3 = __shfl(w11, sA, 32);
    float wA = (cA == 0) ? u0 : (cA == 1) ? u1 : (cA == 2) ? u2 : u3;
    t0 = __shfl(i00, sA + 8, 32); t1 = __shfl(i01, sA + 8, 32);
    t2 = __shfl(i10, sA + 8, 32); t3 = __shfl(i11, sA + 8, 32);
    int addrB = (cA == 0) ? t0 : (cA == 1) ? t1 : (cA == 2) ? t2 : t3;
    u0 = __shfl(w00, sA + 8, 32); u1 = __shfl(w01, sA + 8, 32);
    u2 = __shfl(w10, sA + 8, 32); u3 = __shfl(w11, sA + 8, 32);
    float wB = (cA == 0) ? u0 : (cA == 1) ? u1 : (cA == 2) ? u2 : u3;

    int cl = l >> 3;
    int d4 = l & 7;
    float ax = 0.0f, ay = 0.0f, az = 0.0f, aw = 0.0f;
    #pragma unroll
    for (int s = 0; s < 8; s++) {
        int   a = __shfl(addrA, s * 4 + cl, 32);
        float w = __shfl(wA,    s * 4 + cl, 32);
        float4 v = *(const float4*)(value + a + (d4 << 2));
        ax = fmaf(w, v.x, ax); ay = fmaf(w, v.y, ay);
        az = fmaf(w, v.z, az); aw = fmaf(w, v.w, aw);
    }
    #pragma unroll
    for (int s = 0; s < 8; s++) {
        int   a = __shfl(addrB, s * 4 + cl, 32);
        float w = __shfl(wB,    s * 4 + cl, 32);
        float4 v = *(const float4*)(value + a + (d4 << 2));
        ax = fmaf(w, v.x, ax); ay = fmaf(w, v.y, ay);
        az = fmaf(w, v.z, az); aw = fmaf(w, v.w, aw);
    }
    ax += __shfl_xor(ax, 8, 32);  ay += __shfl_xor(ay, 8, 32);
    az += __shfl_xor(az, 8, 32);  aw += __shfl_xor(aw, 8, 32);
    ax += __shfl_xor(ax, 16, 32); ay += __shfl_xor(ay, 16, 32);
    az += __shfl_xor(az, 16, 32); aw += __shfl_xor(aw, 16, 32);

    if (l < 8) {
        ushort4 o = {f2b(ax), f2b(ay), f2b(az), f2b(aw)};
        *(ushort4*)(out_bf + (size_t)gid * 32 + (d4 << 2)) = o;
    }
}

// ---------------------------------------------------------------------------
// kernel_launch — workspace layout identical to round 4 (verified safe):
//   [q_bf | value | src_bf | offs | logits | weights]; h1_bf == [src_bf, weights)
// ---------------------------------------------------------------------------
extern "C" void kernel_launch(void* const* d_in, const int* in_sizes, int n_in,
                              void* d_out, int out_size, void* d_ws, size_t ws_size,
                              hipStream_t stream)
{
    const float* src  = (const float*)d_in[0];
    const float* pos  = (const float*)d_in[1];
    const float* refp = (const float*)d_in[2];
    const float* n1g = (const float*)d_in[5];
    const float* n1b = (const float*)d_in[6];
    const float* n2g = (const float*)d_in[7];
    const float* n2b = (const float*)d_in[8];
    const float* Wv  = (const float*)d_in[9];
    const float* bv  = (const float*)d_in[10];
    const float* Wof = (const float*)d_in[11];
    const float* bof = (const float*)d_in[12];
    const float* Wat = (const float*)d_in[13];
    const float* bat = (const float*)d_in[14];
    const float* Wo  = (const float*)d_in[15];
    const float* bo  = (const float*)d_in[16];
    const float* Wf1 = (const float*)d_in[17];
    const float* bf1 = (const float*)d_in[18];
    const float* Wf2 = (const float*)d_in[19];
    const float* bf2 = (const float*)d_in[20];
    float* out = (float*)d_out;

    char* ws = (char*)d_ws;
    const int M = MROWS;               // 43520
    const size_t SZ_BF = (size_t)M * 256 * 2;   // 22,282,240
    const size_t SZ_F  = (size_t)M * 256 * 4;   // 44,564,480

    ushort_t* q_bf    = (ushort_t*)(ws);                              // [M,256] bf16
    float*    value   = (float*)   (ws + SZ_BF);                      // [M,256] f32
    ushort_t* src_bf  = (ushort_t*)(ws + SZ_BF + SZ_F);               // [M,256] bf16
    float*    offsb   = (float*)   (ws + 2 * SZ_BF + SZ_F);           // [M,256] f32
    float*    logitsb = (float*)   (ws + 2 * SZ_BF + 2 * SZ_F);       // [M,128] f32
    ushort_t* h0_bf   = q_bf;
    ushort_t* sampled = src_bf;
    float*    src2    = value;
    ushort_t* h1_bf   = src_bf;   // [M,1024] bf16, spans src_bf+offs+logits exactly
    char* wtp = ws + 2 * SZ_BF + 2 * SZ_F + (size_t)M * 128 * 4;
    ushort_t* WvT  = (ushort_t*)(wtp);
    ushort_t* WofT = WvT  + 256 * 256;
    ushort_t* WatT = WofT + 256 * 256;
    ushort_t* WoT  = WatT + 256 * 128;
    ushort_t* Wf1T = WoT  + 256 * 256;
    ushort_t* Wf2T = Wf1T + 256 * 1024;

    // 0) transpose+convert all weights to [N][K] bf16
    TP tp;
    tp.s[0] = Wv;  tp.d[0] = WvT;  tp.K[0] = 256;  tp.N[0] = 256;
    tp.s[1] = Wof; tp.d[1] = WofT; tp.K[1] = 256;  tp.N[1] = 256;
    tp.s[2] = Wat; tp.d[2] = WatT; tp.K[2] = 256;  tp.N[2] = 128;
    tp.s[3] = Wo;  tp.d[3] = WoT;  tp.K[3] = 256;  tp.N[3] = 256;
    tp.s[4] = Wf1; tp.d[4] = Wf1T; tp.K[4] = 256;  tp.N[4] = 1024;
    tp.s[5] = Wf2; tp.d[5] = Wf2T; tp.K[5] = 1024; tp.N[5] = 256;
    tp.start[0] = 0;   tp.start[1] = 64;  tp.start[2] = 128;
    tp.start[3] = 160; tp.start[4] = 224; tp.start[5] = 480; tp.start[6] = 736;
    transpose_convert<<<736, 256, 0, stream>>>(tp);

    // 1) q_bf = bf16(LN1(src) + pos); src_bf = bf16(src)
    ln_dual_kernel<<<M / 4, 256, 0, stream>>>(src, n1g, n1b, pos, q_bf, src_bf);
    // 2) value = src_bf @ Wv + bv   (fp32 out)
    gemm_mfma<0, 0, 0><<<dim3(2, M / 128), 256, 0, stream>>>(
        src_bf, WvT, bv, nullptr, value, nullptr, M, 256, 256);
    // 3) offs = q_bf @ Wof + bof    (fp32 out)
    gemm_mfma<0, 0, 0><<<dim3(2, M / 128), 256, 0, stream>>>(
        q_bf, WofT, bof, nullptr, offsb, nullptr, M, 256, 256);
    // 4) logits = q_bf @ Wat + bat  (fp32 out)
    gemm_mfma<0, 0, 0><<<dim3(1, M / 128), 256, 0, stream>>>(
        q_bf, WatT, bat, nullptr, logitsb, nullptr, M, 128, 256);
    // 5) fused softmax + sampling -> sampled (bf16; offs/logits dead after)
    msdeform_kernel<<<M, 256, 0, stream>>>(value, offsb, logitsb, refp, sampled);
    // 6) src2 = sampled @ Wo + bo + src  (fp32, overwrites value)
    gemm_mfma<0, 1, 0><<<dim3(2, M / 128), 256, 0, stream>>>(
        sampled, WoT, bo, src, src2, nullptr, M, 256, 256);
    // 7) h0_bf = bf16(LN2(src2))
    ln_dual_kernel<<<M / 4, 256, 0, stream>>>(src2, n2g, n2b, nullptr, h0_bf, nullptr);
    // 8) h1_bf = bf16(gelu(h0_bf @ Wf1 + bf1))  (overlays sampled+offs+logits, all dead)
    gemm_mfma<1, 0, 1><<<dim3(8, M / 128), 256, 0, stream>>>(
        h0_bf, Wf1T, bf1, nullptr, nullptr, h1_bf, M, 1024, 256);
    // 9) out = h1_bf @ Wf2 + bf2 + src2  (fp32)
    gemm_mfma<0, 1, 0><<<dim3(2, M / 128), 256, 0, stream>>>(
        h1_bf, Wf2T, bf2, src2, out, nullptr, M, 256, 1024);
}